// Round 7
// baseline (124.876 us; speedup 1.0000x reference)
//
#include <hip/hip_runtime.h>

#define NB 32
#define N0 20000
#define N1 10000
#define N2 10000
#define TILES 625          // 40000 / 64 points per (b, side)
#define KC 8               // centers per block
#define NWAVES 8           // 512 threads
#define TBL_N 256
#define TBL_REP 16         // replica = lane & 15; entry stride 128 B
#define TBL_DOMAIN 2.05f
#define SCALE_B ((float)(128 * TBL_N) / TBL_DOMAIN)   // n -> byte units

// 512 blocks x 512 threads (2 blocks/CU, 32 waves/CU cap): block (b, side, cc)
// exclusively owns out[b*128 + side*64 + cc*8 .. +8) -> no atomics, no memset.
__global__ __launch_bounds__(512, 4) void hat_kernel(
    const float* __restrict__ up0, const float* __restrict__ down0,
    const float* __restrict__ ext0, const float* __restrict__ ext1,
    const float* __restrict__ centers, const float* __restrict__ radius,
    float* __restrict__ out)
{
    const int tid  = threadIdx.x;
    const int lane = tid & 63;
    const int wave = tid >> 6;
    const int bid  = blockIdx.x;
    const int b    = bid >> 4;
    const int side = (bid >> 3) & 1;
    const int cc   = bid & 7;
    const int cbase = cc * KC;

    __shared__ float2 tab[TBL_N * TBL_REP];   // 32 KB
    __shared__ float  red[NWAVES * KC];       // 256 B

    const float r = fabsf(radius[0]);
    const float S = SCALE_B;

    // ---- f32 table: val = A[i] + tt*B[i], tt in byte units.
    // Replica c = lane&15 at byte i*128 + c*8 -> dword banks {2c, 2c+1}:
    // a 16-contiguous-lane phase touches all 32 banks exactly once ->
    // conflict-free (R6's lane>>2 mapping left 24 banks idle per phase).
    if (tid < TBL_N) {
        const float h  = TBL_DOMAIN / (float)TBL_N;
        const float x0 = tid * h, x1 = x0 + h;
        const float g0 = 1.0f/(1.0f+x0) - 1.0f/(1.0f + fabsf(r - x0));
        const float g1 = 1.0f/(1.0f+x1) - 1.0f/(1.0f + fabsf(r - x1));
        const float dT = g1 - g0;
        float2 v;
        v.x = g0 - (float)tid * dT;      // A anchored at t=0
        v.y = dT * (1.0f/128.0f);        // B per byte unit
        #pragma unroll
        for (int c = 0; c < TBL_REP; ++c) tab[tid * TBL_REP + c] = v;
    }
    __syncthreads();

    // centers, rotated (L1 -> Linf) and byte-scaled: wave-uniform -> SGPRs
    float uc[KC], vc[KC];
    #pragma unroll
    for (int k = 0; k < KC; ++k) {
        const float cx = centers[2*(cbase+k)];
        const float cy = centers[2*(cbase+k)+1];
        uc[k] = (cx + cy) * S;
        vc[k] = (cx - cy) * S;
    }
    const float r_b = r * S;   // radius in byte units

    const float2* base0 = (const float2*)((side == 0 ? up0 : down0) + (size_t)b * (N0*2));
    const float2* e0    = (const float2*)(ext0 + (size_t)b * (N1*2));
    const float2* e1    = (const float2*)(ext1 + (size_t)b * (N2*2));

    const int laneoff = (lane & 15) << 3;     // replica byte offset
    const char* tbase = (const char*)tab;

    float acc[KC];
    #pragma unroll
    for (int k = 0; k < KC; ++k) acc[k] = 0.f;

    for (int t = wave; t < TILES; t += NWAVES) {
        const int p = t*64 + lane;
        float px, py;
        if (p < N0) {
            float2 v = base0[p];
            px = v.x; py = v.y;
        } else if (p < N0 + N1) {
            float2 v = e0[p - N0];
            float vv = (side == 0) ? v.y : v.x;   // up uses y, down uses x
            px = vv; py = 1.0f - vv;
        } else {
            float2 v = e1[p - (N0 + N1)];
            float vv = (side == 0) ? v.y : v.x;
            px = vv; py = 1.0f - vv;
        }
        const float u_ = (px + py) * S;   // rotated, byte-scaled
        const float v_ = (px - py) * S;

        #pragma unroll
        for (int k = 0; k < KC; ++k) {
            const float du = u_ - uc[k];
            const float dv = v_ - vc[k];
            const float tt = fmaxf(fabsf(du), fabsf(dv));  // L1 dist, byte units
            if ((k & 3) == 3) {
                // exact path: g = S*(|r-n| - n) / ((S+n)(S+|r-n|)), *S deferred
                const float rn = r_b - tt;
                const float d1 = S + tt;
                const float d2 = S + fabsf(rn);
                const float rc = __builtin_amdgcn_rcpf(d1 * d2);
                acc[k] = fmaf(fabsf(rn) - tt, rc, acc[k]);
            } else {
                const int   iv   = (int)tt;
                const int   addr = (iv & ~127) | laneoff;
                const float2 ab  = *(const float2*)(tbase + addr);  // ds_read_b64
                acc[k] += ab.x;
                acc[k]  = fmaf(tt, ab.y, acc[k]);
            }
        }
    }
    #pragma unroll
    for (int k = 0; k < KC; ++k) if ((k & 3) == 3) acc[k] *= S;  // deferred scale

    // KC=8 butterfly: ends with center (lane>>3)&7 in acc[0] at lanes (lane&7)==0
    {
        #pragma unroll
        for (int k = 0; k < 4; ++k) {
            const bool hi = lane & 32;
            const float send = hi ? acc[k]   : acc[k+4];
            const float keep = hi ? acc[k+4] : acc[k];
            acc[k] = keep + __shfl_xor(send, 32, 64);
        }
        #pragma unroll
        for (int k = 0; k < 2; ++k) {
            const bool hi = lane & 16;
            const float send = hi ? acc[k]   : acc[k+2];
            const float keep = hi ? acc[k+2] : acc[k];
            acc[k] = keep + __shfl_xor(send, 16, 64);
        }
        {
            const bool hi = lane & 8;
            const float send = hi ? acc[0] : acc[1];
            const float keep = hi ? acc[1] : acc[0];
            acc[0] = keep + __shfl_xor(send, 8, 64);
        }
        acc[0] += __shfl_xor(acc[0], 4, 64);
        acc[0] += __shfl_xor(acc[0], 2, 64);
        acc[0] += __shfl_xor(acc[0], 1, 64);
    }
    if ((lane & 7) == 0) red[wave * KC + (lane >> 3)] = acc[0];
    __syncthreads();
    if (tid < KC) {
        float s = 0.f;
        #pragma unroll
        for (int w = 0; w < NWAVES; ++w) s += red[w * KC + tid];
        out[b*128 + side*64 + cbase + tid] = s;   // exclusive direct store
    }
}

__global__ __launch_bounds__(256) void tpl_kernel(float* __restrict__ out)
{
    __shared__ float red[256];
    float s = 0.f;
    for (int i = threadIdx.x; i < NB*64; i += 256) {
        const int b = i >> 6, k = i & 63;
        const float d = out[b*128 + k] - out[b*128 + 64 + k];
        s = fmaf(d, d, s);
    }
    red[threadIdx.x] = s;
    __syncthreads();
    for (int w = 128; w > 0; w >>= 1) {
        if (threadIdx.x < w) red[threadIdx.x] += red[threadIdx.x + w];
        __syncthreads();
    }
    if (threadIdx.x == 0) out[NB*128] = -red[0];
}

extern "C" void kernel_launch(void* const* d_in, const int* in_sizes, int n_in,
                              void* d_out, int out_size, void* d_ws, size_t ws_size,
                              hipStream_t stream) {
    const float* up0     = (const float*)d_in[0];
    const float* down0   = (const float*)d_in[1];
    const float* ext0    = (const float*)d_in[2];
    const float* ext1    = (const float*)d_in[3];
    const float* centers = (const float*)d_in[4];
    const float* radius  = (const float*)d_in[5];
    float* out = (float*)d_out;

    hat_kernel<<<dim3(NB * 16), dim3(512), 0, stream>>>(
        up0, down0, ext0, ext1, centers, radius, out);
    tpl_kernel<<<1, 256, 0, stream>>>(out);
}